// Round 7
// baseline (66.400 us; speedup 1.0000x reference)
//
#include <hip/hip_runtime.h>
#include <hip/hip_bf16.h>
#include <math.h>

// QCONV2d 5x5: out[b,c,h,w] = prod_{p=1..24} cos(x_patch[p] + w[p])
// cos(x+w) = cos(x)cos(w) - sin(x)sin(w): sincos(pixel) once -> LDS float2;
// sincos(w) once per lane -> v_readlane -> wave-uniform SGPRs.
// BARRIER-FREE: each wave owns a 16-row x 32-col output tile and stages its
// own 20x36 halo region into a private LDS slice -> no __syncthreads, no
// block-wide drain; waves' staging/compute interleave freely. Within-wave
// DS ordering is in-order; wave_barrier() pins compiler ordering.
// Zero pad => (cos,sin)=(1,0) => term = cos(w_p) exactly.

#define WROWS 20        // 16 + 2 halo each side
#define WCOLS 36        // 32 + 2 halo each side (288 B/row, 16B-multiple)

__device__ __forceinline__ float rdlane(float v, int lane) {
    return __uint_as_float(__builtin_amdgcn_readlane(__float_as_uint(v), lane));
}

__global__ __launch_bounds__(256)
void qconv5x5_kernel(const float* __restrict__ x, const float* __restrict__ w,
                     float* __restrict__ out)
{
    __shared__ alignas(16) float2 sm[4][WROWS][WCOLS];   // 23 KB, 1 slice/wave

    const int tid  = threadIdx.x;
    const int lane = tid & 63;
    const int q    = tid >> 6;                 // wave in block
    const int W    = blockIdx.x * 4 + q;       // global wave id 0..4095
    const int plane = W >> 3;                  // 512 planes, 8 waves each
    const int sub   = W & 7;
    const int r0    = (sub >> 1) * 16;         // strip start row 0/16/32/48
    const int h     = sub & 1;                 // column half
    const int c0    = h * 32;                  // first output col 0 or 32

    // --- w-trig: one sincos per lane, broadcast via readlane -> SGPRs ---
    float sv, cv;
    __sincosf(w[lane < 25 ? lane : 0], &sv, &cv);
    float cw[25], sw[25];
#pragma unroll
    for (int p = 0; p < 25; ++p) {
        cw[p] = rdlane(cv, p);
        sw[p] = rdlane(sv, p);
    }

    const float* xp = x + plane * 64 * 64;
    float2 (*R)[WCOLS] = sm[q];                // this wave's private slice

    // --- staging: 20 rows x (8 interior float4 slots + 2 halo float2 slots)
    // staged col j <-> global col c0 + j - 2; OOB -> (cos,sin) = (1,0).
    for (int i = lane; i < WROWS * 10; i += 64) {
        const int rr = i / 10;                 // staged row 0..19
        const int t  = i - rr * 10;            // task 0..9
        const int gr = r0 + rr - 2;
        const bool rowok = (unsigned)gr < 64u;
        const float* rowg = xp + gr * 64;
        if (t < 8) {
            // interior: global cols c0+4t .. c0+4t+3 (16B-aligned load)
            float4 px = make_float4(0.f, 0.f, 0.f, 0.f);
            if (rowok) px = *reinterpret_cast<const float4*>(rowg + c0 + 4 * t);
            float s0, c0_, s1, c1_, s2, c2_, s3, c3_;
            __sincosf(px.x, &s0, &c0_);
            __sincosf(px.y, &s1, &c1_);
            __sincosf(px.z, &s2, &c2_);
            __sincosf(px.w, &s3, &c3_);
            float2* dst = &R[rr][4 * t + 2];   // 16B-aligned
            *reinterpret_cast<float4*>(dst)     = make_float4(c0_, s0, c1_, s1);
            *reinterpret_cast<float4*>(dst + 2) = make_float4(c2_, s2, c3_, s3);
        } else if (t == 8) {
            // left halo: global cols c0-2, c0-1 (real iff h==1)
            float2 px = make_float2(0.f, 0.f);
            if (rowok && h == 1)
                px = *reinterpret_cast<const float2*>(rowg + c0 - 2);
            float sa, ca, sb, cb;
            __sincosf((rowok && h == 1) ? px.x : 0.f, &sa, &ca);
            __sincosf((rowok && h == 1) ? px.y : 0.f, &sb, &cb);
            *reinterpret_cast<float4*>(&R[rr][0]) = make_float4(ca, sa, cb, sb);
        } else {
            // right halo: global cols c0+32, c0+33 (real iff h==0)
            float2 px = make_float2(0.f, 0.f);
            if (rowok && h == 0)
                px = *reinterpret_cast<const float2*>(rowg + c0 + 32);
            float sa, ca, sb, cb;
            __sincosf((rowok && h == 0) ? px.x : 0.f, &sa, &ca);
            __sincosf((rowok && h == 0) ? px.y : 0.f, &sb, &cb);
            *reinterpret_cast<float4*>(&R[rr][34]) = make_float4(ca, sa, cb, sb);
        }
    }

    __builtin_amdgcn_wave_barrier();   // ordering fence; DS pipe is in-order
                                       // per wave, data visible after waitcnt

    // --- compute: lane -> col pair cp (cols c0+2cp, +1), row group rg ---
    const int cp = lane & 15;          // 0..15
    const int rg = lane >> 4;          // 0..3, output rows r0+rg*4 .. +3

    float prod[4][2];
#pragma unroll
    for (int ro = 0; ro < 4; ++ro) { prod[ro][0] = 1.f; prod[ro][1] = 1.f; }

    // 8 neighborhood rows feed 4 output rows; output local row rl = rg*4+ro
    // uses staged rows rl..rl+4 (staged row 0 = global row r0-2).
#pragma unroll
    for (int nr = 0; nr < 8; ++nr) {
        const int tr = rg * 4 + nr;
        const float4* rowp = reinterpret_cast<const float4*>(&R[tr][0]);
        float4 f0 = rowp[cp], f1 = rowp[cp + 1], f2 = rowp[cp + 2];
        float2 arr6[6] = { make_float2(f0.x, f0.y), make_float2(f0.z, f0.w),
                           make_float2(f1.x, f1.y), make_float2(f1.z, f1.w),
                           make_float2(f2.x, f2.y), make_float2(f2.z, f2.w) };
#pragma unroll
        for (int ro = 0; ro < 4; ++ro) {
            const int di = nr - ro;
            if (di < 0 || di > 4) continue;
#pragma unroll
            for (int dj = 0; dj < 5; ++dj) {
                const int p = di * 5 + dj;
#pragma unroll
                for (int pa = 0; pa < 2; ++pa) {
                    if (p == 0) continue;          // reference skips patch 0
                    const float2 v = arr6[dj + pa];
                    prod[ro][pa] *= fmaf(v.x, cw[p], -(v.y * sw[p]));
                }
            }
        }
    }

    float2* op = reinterpret_cast<float2*>(
        out + plane * 64 * 64 + (r0 + rg * 4) * 64 + c0 + 2 * cp);
#pragma unroll
    for (int ro = 0; ro < 4; ++ro)
        op[ro * 32] = make_float2(prod[ro][0], prod[ro][1]);
}

extern "C" void kernel_launch(void* const* d_in, const int* in_sizes, int n_in,
                              void* d_out, int out_size, void* d_ws, size_t ws_size,
                              hipStream_t stream) {
    const float* x = (const float*)d_in[0];   // [32,16,64,64] f32
    const float* w = (const float*)d_in[1];   // [25] f32
    float* out = (float*)d_out;               // [32,16,64,64] f32
    (void)in_sizes; (void)n_in; (void)out_size; (void)d_ws; (void)ws_size;

    dim3 grid(1024);                          // 4096 waves = 512 planes x 8 tiles
    dim3 block(256);                          // 4 independent waves/block
    qconv5x5_kernel<<<grid, block, 0, stream>>>(x, w, out);
}

// Round 8
// 63.881 us; speedup vs baseline: 1.0394x; 1.0394x over previous
//
#include <hip/hip_runtime.h>
#include <hip/hip_bf16.h>
#include <math.h>

// QCONV2d 5x5: out[b,c,h,w] = prod_{p=1..24} cos(x_patch[p] + w[p])
// cos(x+w) = cos(x)cos(w) - sin(x)sin(w): sincos(pixel) once -> LDS float2;
// sincos(w) once per lane -> v_readlane -> wave-uniform SGPRs.
// R6 structure — measured best (63.6 us total): TR=32, 1024 blocks,
// 16 waves/CU; branch-free vectorized staging (column halo is ALWAYS
// zero-pad -> constant (1,0); interior via aligned float4 loads, row-OOB ->
// zeroed vector since sincos(0)=(0,1) is exactly the pad value); compute
// reads 3 aligned ds_read_b128 per neighborhood row for a 2-col x 4-row
// output patch per thread. Barrier-free variant (R7) and max-occupancy
// variant (R5) both measured worse; packed-f32 variant (R4) worse.

#define TR   32                 // output rows per block strip
#define SMR  (TR + 4)           // 36 staged rows
#define SMC  (64 + 4)           // 68 staged cols (544 B/row, 16B-multiple)

__device__ __forceinline__ float rdlane(float v, int lane) {
    return __uint_as_float(__builtin_amdgcn_readlane(__float_as_uint(v), lane));
}

__global__ __launch_bounds__(256)
void qconv5x5_kernel(const float* __restrict__ x, const float* __restrict__ w,
                     float* __restrict__ out)
{
    __shared__ alignas(16) float2 sm[SMR][SMC];   // (cos,sin), 19.6 KB

    const int tid   = threadIdx.x;
    const int bid   = blockIdx.x;
    const int plane = bid >> 1;              // 512 planes
    const int r0    = (bid & 1) * TR;        // strip start row: 0 or 32

    // --- w-trig: one sincos per lane, broadcast via readlane -> SGPRs ---
    const int lane = tid & 63;
    float sv, cv;
    __sincosf(w[lane < 25 ? lane : 0], &sv, &cv);
    float cw[25], sw[25];
#pragma unroll
    for (int p = 0; p < 25; ++p) {
        cw[p] = rdlane(cv, p);
        sw[p] = rdlane(sv, p);
    }

    // --- staging ---
    const float* xp = x + plane * 64 * 64;

    // (a) column halo: cols 0,1,66,67 of every staged row = pad (1,0)
    if (tid < SMR * 4) {                     // 144 threads
        const int rr = tid >> 2;
        const int e  = tid & 3;
        const int cc = (e < 2) ? e : 64 + e; // 0,1,66,67
        sm[rr][cc] = make_float2(1.0f, 0.0f);
    }

    // (b) interior: 36 rows x 16 aligned float4 slots; row-OOB -> zeros
    for (int i = tid; i < SMR * 16; i += 256) {
        const int rr = i >> 4;               // 0..35
        const int ss = i & 15;               // 0..15
        const int gr = r0 + rr - 2;
        float4 px = make_float4(0.f, 0.f, 0.f, 0.f);
        if ((unsigned)gr < 64u)
            px = *reinterpret_cast<const float4*>(xp + gr * 64 + 4 * ss);
        float s0, c0, s1, c1, s2, c2, s3, c3;
        __sincosf(px.x, &s0, &c0);
        __sincosf(px.y, &s1, &c1);
        __sincosf(px.z, &s2, &c2);
        __sincosf(px.w, &s3, &c3);
        float2* dst = &sm[rr][4 * ss + 2];   // 16B-aligned
        dst[0] = make_float2(c0, s0);
        dst[1] = make_float2(c1, s1);
        dst[2] = make_float2(c2, s2);
        dst[3] = make_float2(c3, s3);
    }
    __syncthreads();

    // --- compute: col-pair cp (cols 2cp,2cp+1), row-group rq (4 rows) ---
    const int cp = tid & 31;         // 0..31
    const int rq = tid >> 5;         // 0..7, output local rows rq*4..rq*4+3

    float prod[4][2];
#pragma unroll
    for (int ro = 0; ro < 4; ++ro) { prod[ro][0] = 1.f; prod[ro][1] = 1.f; }

    // 8 neighborhood rows feed 4 output rows; output local row rl = rq*4+ro
    // uses staged rows rl..rl+4 (staged row 0 = global row r0-2).
#pragma unroll
    for (int nr = 0; nr < 8; ++nr) {
        const int tr = rq * 4 + nr;
        const float4* rowp = reinterpret_cast<const float4*>(&sm[tr][0]);
        float4 f0 = rowp[cp], f1 = rowp[cp + 1], f2 = rowp[cp + 2];
        float2 arr6[6] = { make_float2(f0.x, f0.y), make_float2(f0.z, f0.w),
                           make_float2(f1.x, f1.y), make_float2(f1.z, f1.w),
                           make_float2(f2.x, f2.y), make_float2(f2.z, f2.w) };
#pragma unroll
        for (int ro = 0; ro < 4; ++ro) {
            const int di = nr - ro;
            if (di < 0 || di > 4) continue;
#pragma unroll
            for (int dj = 0; dj < 5; ++dj) {
                const int p = di * 5 + dj;
#pragma unroll
                for (int pa = 0; pa < 2; ++pa) {
                    if (p == 0) continue;          // reference skips patch 0
                    const float2 v = arr6[dj + pa];
                    prod[ro][pa] *= fmaf(v.x, cw[p], -(v.y * sw[p]));
                }
            }
        }
    }

    float2* op = reinterpret_cast<float2*>(
        out + plane * 64 * 64 + (r0 + rq * 4) * 64 + 2 * cp);
#pragma unroll
    for (int ro = 0; ro < 4; ++ro)
        op[ro * 32] = make_float2(prod[ro][0], prod[ro][1]);
}

extern "C" void kernel_launch(void* const* d_in, const int* in_sizes, int n_in,
                              void* d_out, int out_size, void* d_ws, size_t ws_size,
                              hipStream_t stream) {
    const float* x = (const float*)d_in[0];   // [32,16,64,64] f32
    const float* w = (const float*)d_in[1];   // [25] f32
    float* out = (float*)d_out;               // [32,16,64,64] f32
    (void)in_sizes; (void)n_in; (void)out_size; (void)d_ws; (void)ws_size;

    dim3 grid(512 * (64 / TR));               // 1024 blocks
    dim3 block(256);
    qconv5x5_kernel<<<grid, block, 0, stream>>>(x, w, out);
}